// Round 1
// baseline (935.157 us; speedup 1.0000x reference)
//
#include <hip/hip_runtime.h>
#include <hip/hip_bf16.h>
#include <math.h>

typedef unsigned short u16;
typedef u16 u16x8 __attribute__((ext_vector_type(8)));
typedef __bf16 bf16x8 __attribute__((ext_vector_type(8)));
typedef float f32x4 __attribute__((ext_vector_type(4)));

#define T_SEQ 2048
#define IN_DIM 8192
#define QKV_COLS 6144
#define O_COLS 4096

__device__ __forceinline__ u16 f2bf(float f){
  unsigned u = __builtin_bit_cast(unsigned, f);
  u += 0x7fffu + ((u >> 16) & 1u);   // RNE
  return (u16)(u >> 16);
}
__device__ __forceinline__ float bf2f(u16 h){
  unsigned u = ((unsigned)h) << 16;
  return __builtin_bit_cast(float, u);
}
__device__ __forceinline__ void gload16(const void* g, void* l){
  __builtin_amdgcn_global_load_lds((const __attribute__((address_space(1))) unsigned*)g,
                                   (__attribute__((address_space(3))) unsigned*)l, 16, 0, 0);
}
__device__ __forceinline__ void storeC(float* p, float v){ *p = v; }
__device__ __forceinline__ void storeC(u16* p, float v){ *p = f2bf(v); }

// ---------------- fp32 -> bf16 convert ----------------
__global__ void cvt_f32_bf16(const float* __restrict__ s, u16* __restrict__ d, int n4){
  int stride = gridDim.x * blockDim.x;
  for (int i = blockIdx.x*blockDim.x + threadIdx.x; i < n4; i += stride){
    float4 v = ((const float4*)s)[i];
    ushort4 o;
    o.x = f2bf(v.x); o.y = f2bf(v.y); o.z = f2bf(v.z); o.w = f2bf(v.w);
    ((ushort4*)d)[i] = o;
  }
}

// ---------------- RoPE (+ fold softmax scale into q), in place on bf16 qkv ----------------
__global__ void rope_scale_kernel(u16* __restrict__ qkv, const int* __restrict__ pos){
  __shared__ float cs[64], sn[64];
  int t = blockIdx.x;
  int p = pos[t];
  if (threadIdx.x < 64){
    int i = threadIdx.x;
    double e = (double)(2*i) / 128.0;
    float invf = (float)pow(10000.0, -e);
    float ang = (float)p * invf;     // fp32 product, matches jnp
    cs[i] = cosf(ang);
    sn[i] = sinf(ang);
  }
  __syncthreads();
  u16* row = qkv + (size_t)t * QKV_COLS;
  const float qscale = 0.08838834764831845f;  // D^-0.5
  for (int idx = threadIdx.x; idx < 40*64; idx += blockDim.x){
    int head = idx >> 6, i = idx & 63;
    int base = (head < 32) ? head*128 : 4096 + (head-32)*128;
    float sc = (head < 32) ? qscale : 1.0f;
    float t1 = bf2f(row[base + i]);
    float t2 = bf2f(row[base + i + 64]);
    row[base + i]      = f2bf((t1*cs[i] - t2*sn[i]) * sc);
    row[base + i + 64] = f2bf((t2*cs[i] + t1*sn[i]) * sc);
  }
}

// ---------------- bf16 GEMM, C = A(MxK) * B(NxK)^T, m97 structure ----------------
template<typename OutT>
__global__ __launch_bounds__(256) void gemm_bt(const u16* __restrict__ A, const u16* __restrict__ B,
                                               OutT* __restrict__ C, int M, int N, int K, int ldc){
  __shared__ __attribute__((aligned(16))) u16 Asm[128*32];
  __shared__ __attribute__((aligned(16))) u16 Bsm[128*32];
  const int tid = threadIdx.x;
  const int l = tid & 63, w = tid >> 6;
  const int wm = w >> 1, wn = w & 1;
  const int lr = l & 15, lg = l >> 4;
  const int m0 = blockIdx.y * 128, n0 = blockIdx.x * 128;

  f32x4 acc[4][4] = {};

  const u16* Ag = A + (size_t)(m0 + (tid >> 2)) * K + (tid & 3) * 8;
  const u16* Bg = B + (size_t)(n0 + (tid >> 2)) * K + (tid & 3) * 8;
  u16* As0 = Asm + (w * 64) * 8;   // wave-uniform LDS staging base
  u16* Bs0 = Bsm + (w * 64) * 8;

  const int kiters = K >> 5;
  for (int kt = 0; kt < kiters; ++kt){
    const int kb = kt * 32;
    gload16(Ag + kb, As0);
    gload16(Ag + (size_t)64 * K + kb, As0 + 256*8);
    gload16(Bg + kb, Bs0);
    gload16(Bg + (size_t)64 * K + kb, Bs0 + 256*8);
    __syncthreads();
    bf16x8 af[4], bfr[4];
    #pragma unroll
    for (int mm = 0; mm < 4; ++mm)
      af[mm] = *(const bf16x8*)(Asm + (wm*64 + mm*16 + lr)*32 + lg*8);
    #pragma unroll
    for (int nn = 0; nn < 4; ++nn)
      bfr[nn] = *(const bf16x8*)(Bsm + (wn*64 + nn*16 + lr)*32 + lg*8);
    #pragma unroll
    for (int mm = 0; mm < 4; ++mm)
      #pragma unroll
      for (int nn = 0; nn < 4; ++nn)
        acc[mm][nn] = __builtin_amdgcn_mfma_f32_16x16x32_bf16(af[mm], bfr[nn], acc[mm][nn], 0, 0, 0);
    __syncthreads();
  }
  #pragma unroll
  for (int mm = 0; mm < 4; ++mm)
    #pragma unroll
    for (int nn = 0; nn < 4; ++nn)
      #pragma unroll
      for (int r = 0; r < 4; ++r){
        int row = m0 + wm*64 + mm*16 + lg*4 + r;
        int col = n0 + wn*64 + nn*16 + lr;
        storeC(&C[(size_t)row*ldc + col], acc[mm][nn][r]);
      }
}

// ---------------- causal GQA flash attention ----------------
// block = (q-block of 32 rows, kv-head); 4 waves = the 4 q-heads sharing that kv head.
__global__ __launch_bounds__(256) void attn_kernel(const u16* __restrict__ qkv, u16* __restrict__ ob){
  __shared__ __attribute__((aligned(16))) u16 Ksm[32*128];    // XOR-swizzled, row-major [s][d]
  __shared__ __attribute__((aligned(16))) u16 Vt[128*40];     // transposed [d][s], padded
  __shared__ __attribute__((aligned(16))) u16 Psm[4][32*40];  // per-wave P, padded
  const int tid = threadIdx.x, l = tid & 63, w = tid >> 6;
  const int lr = l & 15, lg = l >> 4;
  const int qb = (gridDim.x - 1) - blockIdx.x;  // heavy blocks dispatched first
  const int kv = blockIdx.y;
  const int h = kv*4 + w;
  const int q0 = qb * 32;

  bf16x8 aq[2][4];  // Q fragments (rows = lane&15, k contiguous)
  #pragma unroll
  for (int mm = 0; mm < 2; ++mm)
    #pragma unroll
    for (int kk = 0; kk < 4; ++kk)
      aq[mm][kk] = *(const bf16x8*)(qkv + (size_t)(q0 + mm*16 + lr)*QKV_COLS + h*128 + kk*32 + lg*8);

  f32x4 oacc[2][8] = {};
  float mrun[2][4], lrun[2][4];
  #pragma unroll
  for (int mm=0;mm<2;mm++)
    #pragma unroll
    for (int r=0;r<4;r++){ mrun[mm][r] = -1e30f; lrun[mm][r] = 0.f; }

  const int cbv = ((tid & 15) << 4) | (tid >> 4);  // V staging: consecutive lanes -> consecutive s
  for (int kt = 0; kt <= qb; ++kt){
    const int s0 = kt * 32;
    // stage K (swizzled: byte ^= (s&7)<<4)
    #pragma unroll
    for (int i = 0; i < 2; ++i){
      int c = tid + i*256, s = c >> 4, dq = c & 15;
      u16x8 kvv = *(const u16x8*)(qkv + (size_t)(s0+s)*QKV_COLS + 4096 + kv*128 + dq*8);
      int lin = (s << 8) + (dq << 4); lin ^= (s & 7) << 4;
      *(u16x8*)((char*)Ksm + lin) = kvv;
    }
    // stage V transposed
    #pragma unroll
    for (int i = 0; i < 2; ++i){
      int c = cbv + i*256, s = c >> 4, dq = c & 15;
      u16x8 vv = *(const u16x8*)(qkv + (size_t)(s0+s)*QKV_COLS + 5120 + kv*128 + dq*8);
      #pragma unroll
      for (int j = 0; j < 8; ++j) Vt[(dq*8+j)*40 + s] = vv[j];
    }
    __syncthreads();

    // QK^T: S[32q x 32s]
    f32x4 sa[2][2] = {};
    #pragma unroll
    for (int kk = 0; kk < 4; ++kk){
      bf16x8 bk[2];
      #pragma unroll
      for (int nn = 0; nn < 2; ++nn){
        int srow = nn*16 + lr;
        int lin = (srow << 8) + (kk << 6) + (lg << 4); lin ^= (srow & 7) << 4;
        bk[nn] = *(const bf16x8*)((char*)Ksm + lin);
      }
      #pragma unroll
      for (int mm = 0; mm < 2; ++mm)
        #pragma unroll
        for (int nn = 0; nn < 2; ++nn)
          sa[mm][nn] = __builtin_amdgcn_mfma_f32_16x16x32_bf16(aq[mm][kk], bk[nn], sa[mm][nn], 0,0,0);
    }

    if (kt == qb){  // diagonal tile: causal mask
      #pragma unroll
      for (int mm=0;mm<2;mm++)
        #pragma unroll
        for (int nn=0;nn<2;nn++)
          #pragma unroll
          for (int r=0;r<4;r++){
            int qrel = mm*16 + lg*4 + r, srel = nn*16 + lr;
            if (srel > qrel) sa[mm][nn][r] = -1e30f;
          }
    }

    // online softmax (row = lane-group; reduce over 16 lanes x 2 n-frags)
    float alph[2][4];
    #pragma unroll
    for (int mm=0;mm<2;mm++)
      #pragma unroll
      for (int r=0;r<4;r++){
        float v = fmaxf(sa[mm][0][r], sa[mm][1][r]);
        v = fmaxf(v, __shfl_xor(v, 1));
        v = fmaxf(v, __shfl_xor(v, 2));
        v = fmaxf(v, __shfl_xor(v, 4));
        v = fmaxf(v, __shfl_xor(v, 8));
        float mn = fmaxf(mrun[mm][r], v);
        float al = __expf(mrun[mm][r] - mn);
        float p0 = __expf(sa[mm][0][r] - mn);
        float p1 = __expf(sa[mm][1][r] - mn);
        sa[mm][0][r] = p0; sa[mm][1][r] = p1;
        float rs = p0 + p1;
        rs += __shfl_xor(rs, 1);
        rs += __shfl_xor(rs, 2);
        rs += __shfl_xor(rs, 4);
        rs += __shfl_xor(rs, 8);
        lrun[mm][r] = lrun[mm][r]*al + rs;
        mrun[mm][r] = mn;
        alph[mm][r] = al;
      }
    #pragma unroll
    for (int mm=0;mm<2;mm++)
      #pragma unroll
      for (int df=0;df<8;df++)
        #pragma unroll
        for (int r=0;r<4;r++)
          oacc[mm][df][r] *= alph[mm][r];

    // P -> per-wave LDS (D-layout scatter), then reload as A-operand
    #pragma unroll
    for (int mm=0;mm<2;mm++)
      #pragma unroll
      for (int nn=0;nn<2;nn++)
        #pragma unroll
        for (int r=0;r<4;r++)
          Psm[w][(mm*16 + lg*4 + r)*40 + nn*16 + lr] = f2bf(sa[mm][nn][r]);

    bf16x8 ap[2];
    #pragma unroll
    for (int mm=0;mm<2;mm++)
      ap[mm] = *(const bf16x8*)(&Psm[w][(mm*16 + lr)*40 + lg*8]);
    #pragma unroll
    for (int df=0;df<8;df++){
      bf16x8 bv = *(const bf16x8*)(&Vt[(df*16 + lr)*40 + lg*8]);
      #pragma unroll
      for (int mm=0;mm<2;mm++)
        oacc[mm][df] = __builtin_amdgcn_mfma_f32_16x16x32_bf16(ap[mm], bv, oacc[mm][df], 0,0,0);
    }
    __syncthreads();
  }

  #pragma unroll
  for (int mm=0;mm<2;mm++)
    #pragma unroll
    for (int df=0;df<8;df++)
      #pragma unroll
      for (int r=0;r<4;r++){
        float val = oacc[mm][df][r] / lrun[mm][r];
        int t = q0 + mm*16 + lg*4 + r;
        int col = h*128 + df*16 + lr;
        ob[(size_t)t*O_COLS + col] = f2bf(val);
      }
}

extern "C" void kernel_launch(void* const* d_in, const int* in_sizes, int n_in,
                              void* d_out, int out_size, void* d_ws, size_t ws_size,
                              hipStream_t stream){
  const float* x  = (const float*)d_in[0];
  const int*   pos= (const int*)d_in[1];
  const float* Wq = (const float*)d_in[2];
  const float* Wk = (const float*)d_in[3];
  const float* Wv = (const float*)d_in[4];
  const float* Wo = (const float*)d_in[5];
  float* out = (float*)d_out;

  char* ws = (char*)d_ws;
  u16* xb   = (u16*)(ws);                 // 2048x8192 bf16   (32 MB)
  u16* wb   = (u16*)(ws + 33554432);      // 6144x8192 bf16   (96 MB): Wq|Wk|Wv rows
  u16* wob  = (u16*)(ws + 134217728);     // 4096x4096 bf16   (32 MB)
  u16* qkv  = (u16*)(ws + 167772160);     // 2048x6144 bf16   (24 MB)
  u16* obuf = (u16*)(ws + 192937984);     // 2048x4096 bf16   (16 MB)

  cvt_f32_bf16<<<2048, 256, 0, stream>>>(x,  xb, (T_SEQ*IN_DIM)/4);
  cvt_f32_bf16<<<2048, 256, 0, stream>>>(Wq, wb, (4096*IN_DIM)/4);
  cvt_f32_bf16<<<1024, 256, 0, stream>>>(Wk, wb + (size_t)4096*IN_DIM, (1024*IN_DIM)/4);
  cvt_f32_bf16<<<1024, 256, 0, stream>>>(Wv, wb + (size_t)5120*IN_DIM, (1024*IN_DIM)/4);
  cvt_f32_bf16<<<2048, 256, 0, stream>>>(Wo, wob, (4096*4096)/4);

  gemm_bt<u16><<<dim3(48,16), 256, 0, stream>>>(xb, wb, qkv, 2048, 6144, 8192, 6144);
  rope_scale_kernel<<<T_SEQ, 256, 0, stream>>>(qkv, pos);
  attn_kernel<<<dim3(64,8), 256, 0, stream>>>(qkv, obuf);
  gemm_bt<float><<<dim3(32,16), 256, 0, stream>>>(obuf, wob, out, 2048, 4096, 4096, 4096);
}

// Round 2
// 919.097 us; speedup vs baseline: 1.0175x; 1.0175x over previous
//
#include <hip/hip_runtime.h>
#include <hip/hip_bf16.h>
#include <math.h>

typedef unsigned short u16;
typedef u16 u16x8 __attribute__((ext_vector_type(8)));
typedef __bf16 bf16x8 __attribute__((ext_vector_type(8)));
typedef float f32x4 __attribute__((ext_vector_type(4)));

#define T_SEQ 2048
#define IN_DIM 8192
#define QKV_COLS 6144
#define O_COLS 4096

__device__ __forceinline__ u16 f2bf(float f){
  unsigned u = __builtin_bit_cast(unsigned, f);
  u += 0x7fffu + ((u >> 16) & 1u);   // RNE
  return (u16)(u >> 16);
}
__device__ __forceinline__ float bf2f(u16 h){
  unsigned u = ((unsigned)h) << 16;
  return __builtin_bit_cast(float, u);
}
__device__ __forceinline__ void gload16(const void* g, void* l){
  __builtin_amdgcn_global_load_lds((const __attribute__((address_space(1))) unsigned*)g,
                                   (__attribute__((address_space(3))) unsigned*)l, 16, 0, 0);
}
__device__ __forceinline__ void storeC(float* p, float v){ *p = v; }
__device__ __forceinline__ void storeC(u16* p, float v){ *p = f2bf(v); }

// ---------------- fused fp32 -> bf16 convert (all 5 tensors, one launch) ----------------
__global__ void cvt_all(const float* __restrict__ x, const float* __restrict__ wq,
                        const float* __restrict__ wk, const float* __restrict__ wv,
                        const float* __restrict__ wo,
                        u16* __restrict__ xb, u16* __restrict__ wb, u16* __restrict__ wob){
  const int NX  = T_SEQ*IN_DIM/4;        // 4,194,304
  const int NQ  = 4096*IN_DIM/4;         // 8,388,608
  const int NKV = 1024*IN_DIM/4;         // 2,097,152
  const int NO  = 4096*4096/4;           // 4,194,304
  const int TOT = NX + NQ + 2*NKV + NO;
  int stride = gridDim.x * blockDim.x;
  for (int i = blockIdx.x*blockDim.x + threadIdx.x; i < TOT; i += stride){
    const float4* s; ushort4* d; int j = i;
    if (j < NX){ s = (const float4*)x; d = (ushort4*)xb; }
    else { j -= NX;
      if (j < NQ){ s = (const float4*)wq; d = (ushort4*)wb; }
      else { j -= NQ;
        if (j < NKV){ s = (const float4*)wk; d = (ushort4*)(wb + (size_t)4096*IN_DIM); }
        else { j -= NKV;
          if (j < NKV){ s = (const float4*)wv; d = (ushort4*)(wb + (size_t)5120*IN_DIM); }
          else { j -= NKV; s = (const float4*)wo; d = (ushort4*)wob; } } } }
    float4 v = s[j];
    ushort4 o; o.x = f2bf(v.x); o.y = f2bf(v.y); o.z = f2bf(v.z); o.w = f2bf(v.w);
    d[j] = o;
  }
}

// ---------------- RoPE (+ fold softmax scale into q), in place on bf16 qkv ----------------
__global__ void rope_scale_kernel(u16* __restrict__ qkv, const int* __restrict__ pos){
  __shared__ float cs[64], sn[64];
  int t = blockIdx.x;
  int p = pos[t];
  if (threadIdx.x < 64){
    int i = threadIdx.x;
    double e = (double)(2*i) / 128.0;
    float invf = (float)pow(10000.0, -e);
    float ang = (float)p * invf;
    cs[i] = cosf(ang);
    sn[i] = sinf(ang);
  }
  __syncthreads();
  u16* row = qkv + (size_t)t * QKV_COLS;
  const float qscale = 0.08838834764831845f;  // D^-0.5
  for (int idx = threadIdx.x; idx < 40*64; idx += blockDim.x){
    int head = idx >> 6, i = idx & 63;
    int base = (head < 32) ? head*128 : 4096 + (head-32)*128;
    float sc = (head < 32) ? qscale : 1.0f;
    float t1 = bf2f(row[base + i]);
    float t2 = bf2f(row[base + i + 64]);
    row[base + i]      = f2bf((t1*cs[i] - t2*sn[i]) * sc);
    row[base + i + 64] = f2bf((t2*cs[i] + t1*sn[i]) * sc);
  }
}

// ---------------- pipelined bf16 GEMM, C = A(MxK) * B(NxK)^T ----------------
// 256x256 tile, BK=32, 4 LDS buffers, 2 phases/tile, counted vmcnt(4) at tile
// boundary (loads stay in flight across barriers), setprio around MFMA cluster.
// LDS rotation swizzle slot' = (slot + (row>>1))&3, applied on BOTH sides:
// pre-permuted global source (global_load_lds dest is linear) + swizzled ds_read.
template<typename OutT>
__global__ __launch_bounds__(512,2) void gemm_pipe(const u16* __restrict__ A, const u16* __restrict__ B,
                                                   OutT* __restrict__ C, int K, int ldc){
  __shared__ __attribute__((aligned(16))) u16 Asm[4*8192];  // 4 bufs x 256 rows x 32 cols
  __shared__ __attribute__((aligned(16))) u16 Bsm[4*8192];
  const int tid = threadIdx.x;
  const int w = tid >> 6, l = tid & 63;
  const int wm = w >> 2, wn = w & 3;           // 2 x 4 wave grid
  const int lr = l & 15, lg = l >> 4;
  const int m0 = blockIdx.y * 256, n0 = blockIdx.x * 256;

  // staging thread constants: thread t writes LDS-linear (row=t>>2, slot'=t&3);
  // it must FETCH the element whose logical slot maps there: s = (slot' - (row>>1))&3
  const int srow  = tid >> 2;                          // 0..127 within half
  const int sslot = ((tid & 3) - ((tid >> 3) & 3)) & 3;
  const u16* Ag = A + (size_t)(m0 + srow) * K + sslot * 8;
  const u16* Bg = B + (size_t)(n0 + srow) * K + sslot * 8;
  char* AsB = (char*)Asm;
  char* BsB = (char*)Bsm;
  const int sdst = w * 1024;                           // wave-uniform byte base within half

  // per-thread ds_read byte offsets (constant; only buf*16384 varies per tile)
  int aoff[4], aoff2[4], boff[4];
  #pragma unroll
  for (int i = 0; i < 4; ++i){
    int ra = wm*128 + i*16 + lr;
    aoff[i]  = ra*64  + (((lg + (ra>>1)) & 3) << 4);
    int ra2 = wm*128 + 64 + i*16 + lr;
    aoff2[i] = ra2*64 + (((lg + (ra2>>1)) & 3) << 4);
    int rb = wn*64 + i*16 + lr;
    boff[i]  = rb*64  + (((lg + (rb>>1)) & 3) << 4);
  }

  f32x4 acc[8][4] = {};
  const int NT = K >> 5;

  // prologue: stage tiles 0 and 1 (A halves then B halves, oldest-first order)
  #pragma unroll
  for (int t = 0; t < 2; ++t){
    gload16(Ag + t*32,                    AsB + t*16384 +        sdst);
    gload16(Ag + (size_t)128*K + t*32,    AsB + t*16384 + 8192 + sdst);
    gload16(Bg + t*32,                    BsB + t*16384 +        sdst);
    gload16(Bg + (size_t)128*K + t*32,    BsB + t*16384 + 8192 + sdst);
  }

  for (int t = 0; t < NT; ++t){
    const int bb = (t & 3) * 16384;
    // ---- tile boundary: counted drain (tile t's 4 halves are the oldest; t+1's 4 stay in flight)
    if (t == NT-1) asm volatile("s_waitcnt vmcnt(0)" ::: "memory");
    else           asm volatile("s_waitcnt vmcnt(4)" ::: "memory");
    __builtin_amdgcn_s_barrier();
    // ---- phase 0: read B[0..3] + A[0..3], stage A halves of tile t+2
    bf16x8 bfr[4], afr[4];
    #pragma unroll
    for (int n = 0; n < 4; ++n) bfr[n] = *(const bf16x8*)(BsB + bb + boff[n]);
    #pragma unroll
    for (int i = 0; i < 4; ++i) afr[i] = *(const bf16x8*)(AsB + bb + aoff[i]);
    if (t + 2 < NT){
      const int nb = ((t+2) & 3) * 16384;
      gload16(Ag + (t+2)*32,                 AsB + nb +        sdst);
      gload16(Ag + (size_t)128*K + (t+2)*32, AsB + nb + 8192 + sdst);
    }
    __builtin_amdgcn_s_barrier();
    __builtin_amdgcn_s_setprio(1);
    #pragma unroll
    for (int i = 0; i < 4; ++i)
      #pragma unroll
      for (int n = 0; n < 4; ++n)
        acc[i][n] = __builtin_amdgcn_mfma_f32_16x16x32_bf16(afr[i], bfr[n], acc[i][n], 0, 0, 0);
    __builtin_amdgcn_s_setprio(0);
    // ---- phase 1: read A[4..7], stage B halves of tile t+2
    bf16x8 afr2[4];
    #pragma unroll
    for (int i = 0; i < 4; ++i) afr2[i] = *(const bf16x8*)(AsB + bb + aoff2[i]);
    if (t + 2 < NT){
      const int nb = ((t+2) & 3) * 16384;
      gload16(Bg + (t+2)*32,                 BsB + nb +        sdst);
      gload16(Bg + (size_t)128*K + (t+2)*32, BsB + nb + 8192 + sdst);
    }
    __builtin_amdgcn_s_barrier();
    __builtin_amdgcn_s_setprio(1);
    #pragma unroll
    for (int i = 0; i < 4; ++i)
      #pragma unroll
      for (int n = 0; n < 4; ++n)
        acc[4+i][n] = __builtin_amdgcn_mfma_f32_16x16x32_bf16(afr2[i], bfr[n], acc[4+i][n], 0, 0, 0);
    __builtin_amdgcn_s_setprio(0);
  }

  // epilogue
  #pragma unroll
  for (int m = 0; m < 8; ++m)
    #pragma unroll
    for (int n = 0; n < 4; ++n)
      #pragma unroll
      for (int r = 0; r < 4; ++r){
        int row = m0 + wm*128 + m*16 + lg*4 + r;
        int col = n0 + wn*64 + n*16 + lr;
        storeC(&C[(size_t)row*ldc + col], acc[m][n][r]);
      }
}

// ---------------- causal GQA flash attention (unchanged this round) ----------------
__global__ __launch_bounds__(256) void attn_kernel(const u16* __restrict__ qkv, u16* __restrict__ ob){
  __shared__ __attribute__((aligned(16))) u16 Ksm[32*128];    // XOR-swizzled, row-major [s][d]
  __shared__ __attribute__((aligned(16))) u16 Vt[128*40];     // transposed [d][s], padded
  __shared__ __attribute__((aligned(16))) u16 Psm[4][32*40];  // per-wave P, padded
  const int tid = threadIdx.x, l = tid & 63, w = tid >> 6;
  const int lr = l & 15, lg = l >> 4;
  const int qb = (gridDim.x - 1) - blockIdx.x;  // heavy blocks dispatched first
  const int kv = blockIdx.y;
  const int h = kv*4 + w;
  const int q0 = qb * 32;

  bf16x8 aq[2][4];
  #pragma unroll
  for (int mm = 0; mm < 2; ++mm)
    #pragma unroll
    for (int kk = 0; kk < 4; ++kk)
      aq[mm][kk] = *(const bf16x8*)(qkv + (size_t)(q0 + mm*16 + lr)*QKV_COLS + h*128 + kk*32 + lg*8);

  f32x4 oacc[2][8] = {};
  float mrun[2][4], lrun[2][4];
  #pragma unroll
  for (int mm=0;mm<2;mm++)
    #pragma unroll
    for (int r=0;r<4;r++){ mrun[mm][r] = -1e30f; lrun[mm][r] = 0.f; }

  const int cbv = ((tid & 15) << 4) | (tid >> 4);
  for (int kt = 0; kt <= qb; ++kt){
    const int s0 = kt * 32;
    #pragma unroll
    for (int i = 0; i < 2; ++i){
      int c = tid + i*256, s = c >> 4, dq = c & 15;
      u16x8 kvv = *(const u16x8*)(qkv + (size_t)(s0+s)*QKV_COLS + 4096 + kv*128 + dq*8);
      int lin = (s << 8) + (dq << 4); lin ^= (s & 7) << 4;
      *(u16x8*)((char*)Ksm + lin) = kvv;
    }
    #pragma unroll
    for (int i = 0; i < 2; ++i){
      int c = cbv + i*256, s = c >> 4, dq = c & 15;
      u16x8 vv = *(const u16x8*)(qkv + (size_t)(s0+s)*QKV_COLS + 5120 + kv*128 + dq*8);
      #pragma unroll
      for (int j = 0; j < 8; ++j) Vt[(dq*8+j)*40 + s] = vv[j];
    }
    __syncthreads();

    f32x4 sa[2][2] = {};
    #pragma unroll
    for (int kk = 0; kk < 4; ++kk){
      bf16x8 bk[2];
      #pragma unroll
      for (int nn = 0; nn < 2; ++nn){
        int srow = nn*16 + lr;
        int lin = (srow << 8) + (kk << 6) + (lg << 4); lin ^= (srow & 7) << 4;
        bk[nn] = *(const bf16x8*)((char*)Ksm + lin);
      }
      #pragma unroll
      for (int mm = 0; mm < 2; ++mm)
        #pragma unroll
        for (int nn = 0; nn < 2; ++nn)
          sa[mm][nn] = __builtin_amdgcn_mfma_f32_16x16x32_bf16(aq[mm][kk], bk[nn], sa[mm][nn], 0,0,0);
    }

    if (kt == qb){
      #pragma unroll
      for (int mm=0;mm<2;mm++)
        #pragma unroll
        for (int nn=0;nn<2;nn++)
          #pragma unroll
          for (int r=0;r<4;r++){
            int qrel = mm*16 + lg*4 + r, srel = nn*16 + lr;
            if (srel > qrel) sa[mm][nn][r] = -1e30f;
          }
    }

    float alph[2][4];
    #pragma unroll
    for (int mm=0;mm<2;mm++)
      #pragma unroll
      for (int r=0;r<4;r++){
        float v = fmaxf(sa[mm][0][r], sa[mm][1][r]);
        v = fmaxf(v, __shfl_xor(v, 1));
        v = fmaxf(v, __shfl_xor(v, 2));
        v = fmaxf(v, __shfl_xor(v, 4));
        v = fmaxf(v, __shfl_xor(v, 8));
        float mn = fmaxf(mrun[mm][r], v);
        float al = __expf(mrun[mm][r] - mn);
        float p0 = __expf(sa[mm][0][r] - mn);
        float p1 = __expf(sa[mm][1][r] - mn);
        sa[mm][0][r] = p0; sa[mm][1][r] = p1;
        float rs = p0 + p1;
        rs += __shfl_xor(rs, 1);
        rs += __shfl_xor(rs, 2);
        rs += __shfl_xor(rs, 4);
        rs += __shfl_xor(rs, 8);
        lrun[mm][r] = lrun[mm][r]*al + rs;
        mrun[mm][r] = mn;
        alph[mm][r] = al;
      }
    #pragma unroll
    for (int mm=0;mm<2;mm++)
      #pragma unroll
      for (int df=0;df<8;df++)
        #pragma unroll
        for (int r=0;r<4;r++)
          oacc[mm][df][r] *= alph[mm][r];

    #pragma unroll
    for (int mm=0;mm<2;mm++)
      #pragma unroll
      for (int nn=0;nn<2;nn++)
        #pragma unroll
        for (int r=0;r<4;r++)
          Psm[w][(mm*16 + lg*4 + r)*40 + nn*16 + lr] = f2bf(sa[mm][nn][r]);

    bf16x8 ap[2];
    #pragma unroll
    for (int mm=0;mm<2;mm++)
      ap[mm] = *(const bf16x8*)(&Psm[w][(mm*16 + lr)*40 + lg*8]);
    #pragma unroll
    for (int df=0;df<8;df++){
      bf16x8 bv = *(const bf16x8*)(&Vt[(df*16 + lr)*40 + lg*8]);
      #pragma unroll
      for (int mm=0;mm<2;mm++)
        oacc[mm][df] = __builtin_amdgcn_mfma_f32_16x16x32_bf16(ap[mm], bv, oacc[mm][df], 0,0,0);
    }
    __syncthreads();
  }

  #pragma unroll
  for (int mm=0;mm<2;mm++)
    #pragma unroll
    for (int df=0;df<8;df++)
      #pragma unroll
      for (int r=0;r<4;r++){
        float val = oacc[mm][df][r] / lrun[mm][r];
        int t = q0 + mm*16 + lg*4 + r;
        int col = h*128 + df*16 + lr;
        ob[(size_t)t*O_COLS + col] = f2bf(val);
      }
}

extern "C" void kernel_launch(void* const* d_in, const int* in_sizes, int n_in,
                              void* d_out, int out_size, void* d_ws, size_t ws_size,
                              hipStream_t stream){
  const float* x  = (const float*)d_in[0];
  const int*   pos= (const int*)d_in[1];
  const float* Wq = (const float*)d_in[2];
  const float* Wk = (const float*)d_in[3];
  const float* Wv = (const float*)d_in[4];
  const float* Wo = (const float*)d_in[5];
  float* out = (float*)d_out;

  char* ws = (char*)d_ws;
  u16* xb   = (u16*)(ws);                 // 2048x8192 bf16   (32 MB)
  u16* wb   = (u16*)(ws + 33554432);      // 6144x8192 bf16   (96 MB): Wq|Wk|Wv rows
  u16* wob  = (u16*)(ws + 134217728);     // 4096x4096 bf16   (32 MB)
  u16* qkv  = (u16*)(ws + 167772160);     // 2048x6144 bf16   (24 MB)
  u16* obuf = (u16*)(ws + 192937984);     // 2048x4096 bf16   (16 MB)

  cvt_all<<<2048, 256, 0, stream>>>(x, Wq, Wk, Wv, Wo, xb, wb, wob);

  gemm_pipe<u16><<<dim3(24,8), 512, 0, stream>>>(xb, wb, qkv, IN_DIM, QKV_COLS);
  rope_scale_kernel<<<T_SEQ, 256, 0, stream>>>(qkv, pos);
  attn_kernel<<<dim3(64,8), 256, 0, stream>>>(qkv, obuf);
  gemm_pipe<float><<<dim3(16,8), 512, 0, stream>>>(obuf, wob, out, O_COLS, O_COLS);
}

// Round 3
// 853.279 us; speedup vs baseline: 1.0960x; 1.0771x over previous
//
#include <hip/hip_runtime.h>
#include <hip/hip_bf16.h>
#include <math.h>

typedef unsigned short u16;
typedef u16 u16x8 __attribute__((ext_vector_type(8)));
typedef __bf16 bf16x8 __attribute__((ext_vector_type(8)));
typedef float f32x4 __attribute__((ext_vector_type(4)));

#define T_SEQ 2048
#define IN_DIM 8192
#define QKV_COLS 6144
#define O_COLS 4096

__device__ __forceinline__ u16 f2bf(float f){
  unsigned u = __builtin_bit_cast(unsigned, f);
  u += 0x7fffu + ((u >> 16) & 1u);   // RNE
  return (u16)(u >> 16);
}
__device__ __forceinline__ float bf2f(u16 h){
  unsigned u = ((unsigned)h) << 16;
  return __builtin_bit_cast(float, u);
}
__device__ __forceinline__ void gload16(const void* g, void* l){
  __builtin_amdgcn_global_load_lds((const __attribute__((address_space(1))) unsigned*)g,
                                   (__attribute__((address_space(3))) unsigned*)l, 16, 0, 0);
}
__device__ __forceinline__ void storeC(float* p, float v){ *p = v; }
__device__ __forceinline__ void storeC(u16* p, float v){ *p = f2bf(v); }

// ---------------- fused fp32 -> bf16 convert (all 5 tensors, one launch) ----------------
__global__ void cvt_all(const float* __restrict__ x, const float* __restrict__ wq,
                        const float* __restrict__ wk, const float* __restrict__ wv,
                        const float* __restrict__ wo,
                        u16* __restrict__ xb, u16* __restrict__ wb, u16* __restrict__ wob){
  const int NX  = T_SEQ*IN_DIM/4;
  const int NQ  = 4096*IN_DIM/4;
  const int NKV = 1024*IN_DIM/4;
  const int NO  = 4096*4096/4;
  const int TOT = NX + NQ + 2*NKV + NO;
  int stride = gridDim.x * blockDim.x;
  for (int i = blockIdx.x*blockDim.x + threadIdx.x; i < TOT; i += stride){
    const float4* s; ushort4* d; int j = i;
    if (j < NX){ s = (const float4*)x; d = (ushort4*)xb; }
    else { j -= NX;
      if (j < NQ){ s = (const float4*)wq; d = (ushort4*)wb; }
      else { j -= NQ;
        if (j < NKV){ s = (const float4*)wk; d = (ushort4*)(wb + (size_t)4096*IN_DIM); }
        else { j -= NKV;
          if (j < NKV){ s = (const float4*)wv; d = (ushort4*)(wb + (size_t)5120*IN_DIM); }
          else { j -= NKV; s = (const float4*)wo; d = (ushort4*)wob; } } } }
    float4 v = s[j];
    ushort4 o; o.x = f2bf(v.x); o.y = f2bf(v.y); o.z = f2bf(v.z); o.w = f2bf(v.w);
    d[j] = o;
  }
}

// ---------------- RoPE (+ fold softmax scale into q), in place on bf16 qkv ----------------
__global__ void rope_scale_kernel(u16* __restrict__ qkv, const int* __restrict__ pos){
  __shared__ float cs[64], sn[64];
  int t = blockIdx.x;
  int p = pos[t];
  if (threadIdx.x < 64){
    int i = threadIdx.x;
    double e = (double)(2*i) / 128.0;
    float invf = (float)pow(10000.0, -e);
    float ang = (float)p * invf;
    cs[i] = cosf(ang);
    sn[i] = sinf(ang);
  }
  __syncthreads();
  u16* row = qkv + (size_t)t * QKV_COLS;
  const float qscale = 0.08838834764831845f;  // D^-0.5
  for (int idx = threadIdx.x; idx < 40*64; idx += blockDim.x){
    int head = idx >> 6, i = idx & 63;
    int base = (head < 32) ? head*128 : 4096 + (head-32)*128;
    float sc = (head < 32) ? qscale : 1.0f;
    float t1 = bf2f(row[base + i]);
    float t2 = bf2f(row[base + i + 64]);
    row[base + i]      = f2bf((t1*cs[i] - t2*sn[i]) * sc);
    row[base + i + 64] = f2bf((t2*cs[i] + t1*sn[i]) * sc);
  }
}

// ---------------- pipelined bf16 GEMM, C = A(MxK) * B(NxK)^T ----------------
// Tile 256 x (NFRAG*64). 8 waves (2 M x 4 N), wave tile 128 x NFRAG*16.
// BK=32, 4 LDS buffers, ONE barrier per K-tile (buffer reuse distance = 2 tiles,
// barrier drift < 1 tile => safe). Counted per-wave vmcnt at tile boundary keeps
// next tile's loads in flight across the barrier. Rotation swizzle
// slot' = (slot + (row>>1))&3 on both stage-source and ds_read side.
template<typename OutT, int NFRAG>
__global__ __launch_bounds__(512,2) void gemm_pipe(const u16* __restrict__ A, const u16* __restrict__ B,
                                                   OutT* __restrict__ C, int K, int ldc, int ntile_n){
  __shared__ __attribute__((aligned(16))) u16 Asm[4*8192];          // 4 bufs x 256 x 32
  __shared__ __attribute__((aligned(16))) u16 Bsm[4*NFRAG*2048];    // 4 bufs x NFRAG*64 x 32
  const int tid = threadIdx.x;
  const int w = tid >> 6, l = tid & 63;
  const int wm = w >> 2, wn = w & 3;
  const int lr = l & 15, lg = l >> 4;
  const int id = blockIdx.x;
  const int m0 = (id & 7) * 256;          // XCD-chunked: id%8 = XCD = M-row => A panel L2-resident
  const int n0 = (id >> 3) * (NFRAG*64);
  const int BBUF = NFRAG*4096;            // bytes per B buffer

  // staging: thread t writes LDS-linear (row=tid>>2, physslot=tid&3); fetch the
  // global slot that maps there: s = (physslot - (row>>1))&3  (row>>1 == tid>>3 mod 4)
  const int srow  = tid >> 2;
  const int sslot = ((tid & 3) - ((tid >> 3) & 3)) & 3;
  const u16* Ag  = A + (size_t)(m0 + srow) * K + sslot * 8;
  const u16* Bg  = B + (size_t)(n0 + srow) * K + sslot * 8;
  const u16* Bg2 = B + (size_t)(n0 + 128 + srow) * K + sslot * 8;   // only for NFRAG==3, tid<256
  char* AsB = (char*)Asm;
  char* BsB = (char*)Bsm;
  const int sdst = w * 1024;

  // per-thread ds_read byte offsets (add buf offset per tile)
  int aoff[8], boff[NFRAG];
  #pragma unroll
  for (int i = 0; i < 8; ++i){
    int ra = wm*128 + i*16 + lr;
    aoff[i] = ra*64 + (((lg + (ra>>1)) & 3) << 4);
  }
  #pragma unroll
  for (int i = 0; i < NFRAG; ++i){
    int rb = wn*(NFRAG*16) + i*16 + lr;
    boff[i] = rb*64 + (((lg + (rb>>1)) & 3) << 4);
  }

  f32x4 acc[8][NFRAG];
  #pragma unroll
  for (int m = 0; m < 8; ++m)
    #pragma unroll
    for (int n = 0; n < NFRAG; ++n)
      acc[m][n] = (f32x4){0.f,0.f,0.f,0.f};

  const int NT = K >> 5;

  // per-wave loads per tile (issue order: A0, A1, B0, [B1])
  #define STAGE_TILE(tt) do { \
    const int nb_ = ((tt) & 3); \
    gload16(Ag + (tt)*32,                 AsB + nb_*16384 +        sdst); \
    gload16(Ag + (size_t)128*K + (tt)*32, AsB + nb_*16384 + 8192 + sdst); \
    gload16(Bg + (tt)*32,                 BsB + nb_*BBUF +         sdst); \
    if (NFRAG == 3 && tid < 256) \
      gload16(Bg2 + (tt)*32,              BsB + nb_*BBUF + 8192 +  sdst); \
  } while(0)

  STAGE_TILE(0);
  STAGE_TILE(1);

  for (int t = 0; t < NT; ++t){
    const int ab = (t & 3) * 16384;
    const int bb = (t & 3) * BBUF;
    // tile boundary: drain this tile's loads only (next tile's stay in flight)
    if (t == NT-1){
      asm volatile("s_waitcnt vmcnt(0)" ::: "memory");
    } else if (NFRAG == 3){
      if (w < 4) asm volatile("s_waitcnt vmcnt(4)" ::: "memory");
      else       asm volatile("s_waitcnt vmcnt(3)" ::: "memory");
    } else {
      asm volatile("s_waitcnt vmcnt(3)" ::: "memory");
    }
    __builtin_amdgcn_s_barrier();
    __builtin_amdgcn_sched_barrier(0);

    bf16x8 bfr[NFRAG], afr[8];
    #pragma unroll
    for (int n = 0; n < NFRAG; ++n) bfr[n] = *(const bf16x8*)(BsB + bb + boff[n]);
    #pragma unroll
    for (int i = 0; i < 8; ++i)     afr[i] = *(const bf16x8*)(AsB + ab + aoff[i]);

    if (t + 2 < NT) STAGE_TILE(t+2);

    __builtin_amdgcn_s_setprio(1);
    #pragma unroll
    for (int i = 0; i < 8; ++i)
      #pragma unroll
      for (int n = 0; n < NFRAG; ++n)
        acc[i][n] = __builtin_amdgcn_mfma_f32_16x16x32_bf16(afr[i], bfr[n], acc[i][n], 0, 0, 0);
    __builtin_amdgcn_s_setprio(0);
  }
  #undef STAGE_TILE

  #pragma unroll
  for (int m = 0; m < 8; ++m)
    #pragma unroll
    for (int n = 0; n < NFRAG; ++n)
      #pragma unroll
      for (int r = 0; r < 4; ++r){
        int row = m0 + wm*128 + m*16 + lg*4 + r;
        int col = n0 + wn*(NFRAG*16) + n*16 + lr;
        storeC(&C[(size_t)row*ldc + col], acc[m][n][r]);
      }
}

// ---------------- causal GQA flash attention (unchanged this round) ----------------
__global__ __launch_bounds__(256) void attn_kernel(const u16* __restrict__ qkv, u16* __restrict__ ob){
  __shared__ __attribute__((aligned(16))) u16 Ksm[32*128];
  __shared__ __attribute__((aligned(16))) u16 Vt[128*40];
  __shared__ __attribute__((aligned(16))) u16 Psm[4][32*40];
  const int tid = threadIdx.x, l = tid & 63, w = tid >> 6;
  const int lr = l & 15, lg = l >> 4;
  const int qb = (gridDim.x - 1) - blockIdx.x;
  const int kv = blockIdx.y;
  const int h = kv*4 + w;
  const int q0 = qb * 32;

  bf16x8 aq[2][4];
  #pragma unroll
  for (int mm = 0; mm < 2; ++mm)
    #pragma unroll
    for (int kk = 0; kk < 4; ++kk)
      aq[mm][kk] = *(const bf16x8*)(qkv + (size_t)(q0 + mm*16 + lr)*QKV_COLS + h*128 + kk*32 + lg*8);

  f32x4 oacc[2][8] = {};
  float mrun[2][4], lrun[2][4];
  #pragma unroll
  for (int mm=0;mm<2;mm++)
    #pragma unroll
    for (int r=0;r<4;r++){ mrun[mm][r] = -1e30f; lrun[mm][r] = 0.f; }

  const int cbv = ((tid & 15) << 4) | (tid >> 4);
  for (int kt = 0; kt <= qb; ++kt){
    const int s0 = kt * 32;
    #pragma unroll
    for (int i = 0; i < 2; ++i){
      int c = tid + i*256, s = c >> 4, dq = c & 15;
      u16x8 kvv = *(const u16x8*)(qkv + (size_t)(s0+s)*QKV_COLS + 4096 + kv*128 + dq*8);
      int lin = (s << 8) + (dq << 4); lin ^= (s & 7) << 4;
      *(u16x8*)((char*)Ksm + lin) = kvv;
    }
    #pragma unroll
    for (int i = 0; i < 2; ++i){
      int c = cbv + i*256, s = c >> 4, dq = c & 15;
      u16x8 vv = *(const u16x8*)(qkv + (size_t)(s0+s)*QKV_COLS + 5120 + kv*128 + dq*8);
      #pragma unroll
      for (int j = 0; j < 8; ++j) Vt[(dq*8+j)*40 + s] = vv[j];
    }
    __syncthreads();

    f32x4 sa[2][2] = {};
    #pragma unroll
    for (int kk = 0; kk < 4; ++kk){
      bf16x8 bk[2];
      #pragma unroll
      for (int nn = 0; nn < 2; ++nn){
        int srow = nn*16 + lr;
        int lin = (srow << 8) + (kk << 6) + (lg << 4); lin ^= (srow & 7) << 4;
        bk[nn] = *(const bf16x8*)((char*)Ksm + lin);
      }
      #pragma unroll
      for (int mm = 0; mm < 2; ++mm)
        #pragma unroll
        for (int nn = 0; nn < 2; ++nn)
          sa[mm][nn] = __builtin_amdgcn_mfma_f32_16x16x32_bf16(aq[mm][kk], bk[nn], sa[mm][nn], 0,0,0);
    }

    if (kt == qb){
      #pragma unroll
      for (int mm=0;mm<2;mm++)
        #pragma unroll
        for (int nn=0;nn<2;nn++)
          #pragma unroll
          for (int r=0;r<4;r++){
            int qrel = mm*16 + lg*4 + r, srel = nn*16 + lr;
            if (srel > qrel) sa[mm][nn][r] = -1e30f;
          }
    }

    float alph[2][4];
    #pragma unroll
    for (int mm=0;mm<2;mm++)
      #pragma unroll
      for (int r=0;r<4;r++){
        float v = fmaxf(sa[mm][0][r], sa[mm][1][r]);
        v = fmaxf(v, __shfl_xor(v, 1));
        v = fmaxf(v, __shfl_xor(v, 2));
        v = fmaxf(v, __shfl_xor(v, 4));
        v = fmaxf(v, __shfl_xor(v, 8));
        float mn = fmaxf(mrun[mm][r], v);
        float al = __expf(mrun[mm][r] - mn);
        float p0 = __expf(sa[mm][0][r] - mn);
        float p1 = __expf(sa[mm][1][r] - mn);
        sa[mm][0][r] = p0; sa[mm][1][r] = p1;
        float rs = p0 + p1;
        rs += __shfl_xor(rs, 1);
        rs += __shfl_xor(rs, 2);
        rs += __shfl_xor(rs, 4);
        rs += __shfl_xor(rs, 8);
        lrun[mm][r] = lrun[mm][r]*al + rs;
        mrun[mm][r] = mn;
        alph[mm][r] = al;
      }
    #pragma unroll
    for (int mm=0;mm<2;mm++)
      #pragma unroll
      for (int df=0;df<8;df++)
        #pragma unroll
        for (int r=0;r<4;r++)
          oacc[mm][df][r] *= alph[mm][r];

    #pragma unroll
    for (int mm=0;mm<2;mm++)
      #pragma unroll
      for (int nn=0;nn<2;nn++)
        #pragma unroll
        for (int r=0;r<4;r++)
          Psm[w][(mm*16 + lg*4 + r)*40 + nn*16 + lr] = f2bf(sa[mm][nn][r]);

    bf16x8 ap[2];
    #pragma unroll
    for (int mm=0;mm<2;mm++)
      ap[mm] = *(const bf16x8*)(&Psm[w][(mm*16 + lr)*40 + lg*8]);
    #pragma unroll
    for (int df=0;df<8;df++){
      bf16x8 bv = *(const bf16x8*)(&Vt[(df*16 + lr)*40 + lg*8]);
      #pragma unroll
      for (int mm=0;mm<2;mm++)
        oacc[mm][df] = __builtin_amdgcn_mfma_f32_16x16x32_bf16(ap[mm], bv, oacc[mm][df], 0,0,0);
    }
    __syncthreads();
  }

  #pragma unroll
  for (int mm=0;mm<2;mm++)
    #pragma unroll
    for (int df=0;df<8;df++)
      #pragma unroll
      for (int r=0;r<4;r++){
        float val = oacc[mm][df][r] / lrun[mm][r];
        int t = q0 + mm*16 + lg*4 + r;
        int col = h*128 + df*16 + lr;
        ob[(size_t)t*O_COLS + col] = f2bf(val);
      }
}

extern "C" void kernel_launch(void* const* d_in, const int* in_sizes, int n_in,
                              void* d_out, int out_size, void* d_ws, size_t ws_size,
                              hipStream_t stream){
  const float* x  = (const float*)d_in[0];
  const int*   pos= (const int*)d_in[1];
  const float* Wq = (const float*)d_in[2];
  const float* Wk = (const float*)d_in[3];
  const float* Wv = (const float*)d_in[4];
  const float* Wo = (const float*)d_in[5];
  float* out = (float*)d_out;

  char* ws = (char*)d_ws;
  u16* xb   = (u16*)(ws);                 // 2048x8192 bf16   (32 MB)
  u16* wb   = (u16*)(ws + 33554432);      // 6144x8192 bf16   (96 MB): Wq|Wk|Wv rows
  u16* wob  = (u16*)(ws + 134217728);     // 4096x4096 bf16   (32 MB)
  u16* qkv  = (u16*)(ws + 167772160);     // 2048x6144 bf16   (24 MB)
  u16* obuf = (u16*)(ws + 192937984);     // 2048x4096 bf16   (16 MB)

  cvt_all<<<2048, 256, 0, stream>>>(x, Wq, Wk, Wv, Wo, xb, wb, wob);

  gemm_pipe<u16,3><<<256, 512, 0, stream>>>(xb, wb, qkv, IN_DIM, QKV_COLS, 32);
  rope_scale_kernel<<<T_SEQ, 256, 0, stream>>>(qkv, pos);
  attn_kernel<<<dim3(64,8), 256, 0, stream>>>(qkv, obuf);
  gemm_pipe<float,2><<<256, 512, 0, stream>>>(obuf, wob, out, O_COLS, O_COLS, 32);
}

// Round 5
// 782.458 us; speedup vs baseline: 1.1952x; 1.0905x over previous
//
#include <hip/hip_runtime.h>
#include <hip/hip_bf16.h>
#include <math.h>

typedef unsigned short u16;
typedef u16 u16x8 __attribute__((ext_vector_type(8)));
typedef __bf16 bf16x8 __attribute__((ext_vector_type(8)));
typedef float f32x4 __attribute__((ext_vector_type(4)));

#define T_SEQ 2048
#define IN_DIM 8192
#define QKV_COLS 6144
#define O_COLS 4096

__device__ __forceinline__ u16 f2bf(float f){
  unsigned u = __builtin_bit_cast(unsigned, f);
  u += 0x7fffu + ((u >> 16) & 1u);   // RNE
  return (u16)(u >> 16);
}
__device__ __forceinline__ float bf2f(u16 h){
  unsigned u = ((unsigned)h) << 16;
  return __builtin_bit_cast(float, u);
}
__device__ __forceinline__ void gload16(const void* g, void* l){
  __builtin_amdgcn_global_load_lds((const __attribute__((address_space(1))) unsigned*)g,
                                   (__attribute__((address_space(3))) unsigned*)l, 16, 0, 0);
}
__device__ __forceinline__ void storeC(float* p, float v){ *p = v; }
__device__ __forceinline__ void storeC(u16* p, float v){ *p = f2bf(v); }

// ---------------- fused fp32 -> bf16 convert ----------------
__global__ void cvt_all(const float* __restrict__ x, const float* __restrict__ wq,
                        const float* __restrict__ wk, const float* __restrict__ wv,
                        const float* __restrict__ wo,
                        u16* __restrict__ xb, u16* __restrict__ wb, u16* __restrict__ wob){
  const int NX  = T_SEQ*IN_DIM/4;
  const int NQ  = 4096*IN_DIM/4;
  const int NKV = 1024*IN_DIM/4;
  const int NO  = 4096*4096/4;
  const int TOT = NX + NQ + 2*NKV + NO;
  int stride = gridDim.x * blockDim.x;
  for (int i = blockIdx.x*blockDim.x + threadIdx.x; i < TOT; i += stride){
    const float4* s; ushort4* d; int j = i;
    if (j < NX){ s = (const float4*)x; d = (ushort4*)xb; }
    else { j -= NX;
      if (j < NQ){ s = (const float4*)wq; d = (ushort4*)wb; }
      else { j -= NQ;
        if (j < NKV){ s = (const float4*)wk; d = (ushort4*)(wb + (size_t)4096*IN_DIM); }
        else { j -= NKV;
          if (j < NKV){ s = (const float4*)wv; d = (ushort4*)(wb + (size_t)5120*IN_DIM); }
          else { j -= NKV; s = (const float4*)wo; d = (ushort4*)wob; } } } }
    float4 v = s[j];
    ushort4 o; o.x = f2bf(v.x); o.y = f2bf(v.y); o.z = f2bf(v.z); o.w = f2bf(v.w);
    d[j] = o;
  }
}

// ---------------- RoPE (+ fold softmax scale into q) ----------------
__global__ void rope_scale_kernel(u16* __restrict__ qkv, const int* __restrict__ pos){
  __shared__ float cs[64], sn[64];
  int t = blockIdx.x;
  int p = pos[t];
  if (threadIdx.x < 64){
    int i = threadIdx.x;
    double e = (double)(2*i) / 128.0;
    float invf = (float)pow(10000.0, -e);
    float ang = (float)p * invf;
    cs[i] = cosf(ang);
    sn[i] = sinf(ang);
  }
  __syncthreads();
  u16* row = qkv + (size_t)t * QKV_COLS;
  const float qscale = 0.08838834764831845f;  // D^-0.5
  for (int idx = threadIdx.x; idx < 40*64; idx += blockDim.x){
    int head = idx >> 6, i = idx & 63;
    int base = (head < 32) ? head*128 : 4096 + (head-32)*128;
    float sc = (head < 32) ? qscale : 1.0f;
    float t1 = bf2f(row[base + i]);
    float t2 = bf2f(row[base + i + 64]);
    row[base + i]      = f2bf((t1*cs[i] - t2*sn[i]) * sc);
    row[base + i + 64] = f2bf((t2*cs[i] + t1*sn[i]) * sc);
  }
}

// ---------------- V transpose: qkv V cols -> vtg[kv][d][t] ----------------
__global__ void transpose_v(const u16* __restrict__ qkv, u16* __restrict__ vtg){
  __shared__ u16 tl[128][72];
  const int head = blockIdx.y;     // kv head
  const int st = blockIdx.x;       // 64-wide s tile
  const int tid = threadIdx.x;
  #pragma unroll
  for (int i = 0; i < 4; ++i){
    int c = tid + i*256, s = c >> 4, dq = c & 15;
    u16x8 v = *(const u16x8*)(qkv + (size_t)(st*64+s)*QKV_COLS + 5120 + head*128 + dq*8);
    #pragma unroll
    for (int j = 0; j < 8; ++j) tl[dq*8+j][s] = v[j];
  }
  __syncthreads();
  #pragma unroll
  for (int i = 0; i < 4; ++i){
    int c = tid + i*256, d = c >> 3, sq = c & 7;
    u16x8 v;
    #pragma unroll
    for (int j = 0; j < 8; ++j) v[j] = tl[d][sq*8+j];
    *(u16x8*)(vtg + (size_t)head*262144 + (size_t)d*2048 + st*64 + sq*8) = v;
  }
}

// ---------------- pipelined bf16 GEMM (unchanged from round 3) ----------------
template<typename OutT, int NFRAG>
__global__ __launch_bounds__(512,2) void gemm_pipe(const u16* __restrict__ A, const u16* __restrict__ B,
                                                   OutT* __restrict__ C, int K, int ldc, int ntile_n){
  __shared__ __attribute__((aligned(16))) u16 Asm[4*8192];
  __shared__ __attribute__((aligned(16))) u16 Bsm[4*NFRAG*2048];
  const int tid = threadIdx.x;
  const int w = tid >> 6, l = tid & 63;
  const int wm = w >> 2, wn = w & 3;
  const int lr = l & 15, lg = l >> 4;
  const int id = blockIdx.x;
  const int m0 = (id & 7) * 256;
  const int n0 = (id >> 3) * (NFRAG*64);
  const int BBUF = NFRAG*4096;

  const int srow  = tid >> 2;
  const int sslot = ((tid & 3) - ((tid >> 3) & 3)) & 3;
  const u16* Ag  = A + (size_t)(m0 + srow) * K + sslot * 8;
  const u16* Bg  = B + (size_t)(n0 + srow) * K + sslot * 8;
  const u16* Bg2 = B + (size_t)(n0 + 128 + srow) * K + sslot * 8;
  char* AsB = (char*)Asm;
  char* BsB = (char*)Bsm;
  const int sdst = w * 1024;

  int aoff[8], boff[NFRAG];
  #pragma unroll
  for (int i = 0; i < 8; ++i){
    int ra = wm*128 + i*16 + lr;
    aoff[i] = ra*64 + (((lg + (ra>>1)) & 3) << 4);
  }
  #pragma unroll
  for (int i = 0; i < NFRAG; ++i){
    int rb = wn*(NFRAG*16) + i*16 + lr;
    boff[i] = rb*64 + (((lg + (rb>>1)) & 3) << 4);
  }

  f32x4 acc[8][NFRAG];
  #pragma unroll
  for (int m = 0; m < 8; ++m)
    #pragma unroll
    for (int n = 0; n < NFRAG; ++n)
      acc[m][n] = (f32x4){0.f,0.f,0.f,0.f};

  const int NT = K >> 5;

  #define STAGE_TILE(tt) do { \
    const int nb_ = ((tt) & 3); \
    gload16(Ag + (tt)*32,                 AsB + nb_*16384 +        sdst); \
    gload16(Ag + (size_t)128*K + (tt)*32, AsB + nb_*16384 + 8192 + sdst); \
    gload16(Bg + (tt)*32,                 BsB + nb_*BBUF +         sdst); \
    if (NFRAG == 3 && tid < 256) \
      gload16(Bg2 + (tt)*32,              BsB + nb_*BBUF + 8192 +  sdst); \
  } while(0)

  STAGE_TILE(0);
  STAGE_TILE(1);

  for (int t = 0; t < NT; ++t){
    const int ab = (t & 3) * 16384;
    const int bb = (t & 3) * BBUF;
    if (t == NT-1){
      asm volatile("s_waitcnt vmcnt(0)" ::: "memory");
    } else if (NFRAG == 3){
      if (w < 4) asm volatile("s_waitcnt vmcnt(4)" ::: "memory");
      else       asm volatile("s_waitcnt vmcnt(3)" ::: "memory");
    } else {
      asm volatile("s_waitcnt vmcnt(3)" ::: "memory");
    }
    __builtin_amdgcn_s_barrier();
    __builtin_amdgcn_sched_barrier(0);

    bf16x8 bfr[NFRAG], afr[8];
    #pragma unroll
    for (int n = 0; n < NFRAG; ++n) bfr[n] = *(const bf16x8*)(BsB + bb + boff[n]);
    #pragma unroll
    for (int i = 0; i < 8; ++i)     afr[i] = *(const bf16x8*)(AsB + ab + aoff[i]);

    if (t + 2 < NT) STAGE_TILE(t+2);

    __builtin_amdgcn_s_setprio(1);
    #pragma unroll
    for (int i = 0; i < 8; ++i)
      #pragma unroll
      for (int n = 0; n < NFRAG; ++n)
        acc[i][n] = __builtin_amdgcn_mfma_f32_16x16x32_bf16(afr[i], bfr[n], acc[i][n], 0, 0, 0);
    __builtin_amdgcn_s_setprio(0);
  }
  #undef STAGE_TILE

  #pragma unroll
  for (int m = 0; m < 8; ++m)
    #pragma unroll
    for (int n = 0; n < NFRAG; ++n)
      #pragma unroll
      for (int r = 0; r < 4; ++r){
        int row = m0 + wm*128 + m*16 + lg*4 + r;
        int col = n0 + wn*(NFRAG*16) + n*16 + lr;
        storeC(&C[(size_t)row*ldc + col], acc[m][n][r]);
      }
}

// ---------------- causal GQA flash attention v2 ----------------
// KVBLK=64, K double-buffered + V single-buffered global_load_lds staging with
// counted vmcnt (queue: K(t),V(t),K(t+1)), XOR chunk-swizzle on K and V^T,
// softmax overlapped with V drain, 3 barriers/iter, 2 blocks/CU.
__global__ __launch_bounds__(256,2) void attn2(const u16* __restrict__ qkv, const u16* __restrict__ vtg,
                                               u16* __restrict__ ob){
  __shared__ __attribute__((aligned(16))) u16 Ksm[2*64*128];   // 32 KB, chunk ^= (s&7)
  __shared__ __attribute__((aligned(16))) u16 Vsm[128*64];     // 16 KB, chunk ^= (d&7)
  __shared__ __attribute__((aligned(16))) u16 Psm[4][32*72];   // 18 KB
  const int tid = threadIdx.x, l = tid & 63, w = tid >> 6;
  const int lr = l & 15, lg = l >> 4;
  const int qb = 63 - (int)blockIdx.x;      // heavy blocks first
  const int kv = blockIdx.y;
  const int h = kv*4 + w;
  const int q0 = qb * 32;
  const int lastkt = (qb*32 + 31) >> 6;

  // Q fragments (rope'd, scale folded)
  bf16x8 aq[2][4];
  #pragma unroll
  for (int mm = 0; mm < 2; ++mm)
    #pragma unroll
    for (int kk = 0; kk < 4; ++kk)
      aq[mm][kk] = *(const bf16x8*)(qkv + (size_t)(q0 + mm*16 + lr)*QKV_COLS + h*128 + kk*32 + lg*8);

  // staging sources (pre-swizzled so linear LDS dest yields swizzled layout)
  const u16* Ksrc[4]; const u16* Vsrc[4];
  #pragma unroll
  for (int i = 0; i < 4; ++i){
    int c = (i*4 + w)*64 + l;
    int s = c >> 4, cp = c & 15;
    Ksrc[i] = qkv + (size_t)s*QKV_COLS + 4096 + kv*128 + ((cp ^ (s & 7)) * 8);
    int d = c >> 3, cp2 = c & 7;
    Vsrc[i] = vtg + (size_t)kv*262144 + (size_t)d*2048 + ((cp2 ^ (d & 7)) * 8);
  }
  char* KsB = (char*)Ksm;
  char* VsB = (char*)Vsm;

  #define STAGE_K(kt) do { const int bo_ = ((kt)&1)*16384; \
    _Pragma("unroll") for (int i_ = 0; i_ < 4; ++i_) \
      gload16(Ksrc[i_] + (size_t)(kt)*64*QKV_COLS, KsB + bo_ + (i_*4+w)*1024); } while(0)
  #define STAGE_V(kt) do { \
    _Pragma("unroll") for (int i_ = 0; i_ < 4; ++i_) \
      gload16(Vsrc[i_] + (kt)*64, VsB + (i_*4+w)*1024); } while(0)

  STAGE_K(0);
  STAGE_V(0);
  if (lastkt >= 1) STAGE_K(1);

  f32x4 oacc[2][8] = {};
  float mrun[2][4], lrun[2][4];
  #pragma unroll
  for (int mm = 0; mm < 2; ++mm)
    #pragma unroll
    for (int r = 0; r < 4; ++r){ mrun[mm][r] = -1e30f; lrun[mm][r] = 0.f; }

  for (int kt = 0; kt <= lastkt; ++kt){
    // ---- drain K(kt); keep V(kt)[,K(kt+1)] in flight
    if (kt < lastkt) asm volatile("s_waitcnt vmcnt(8)" ::: "memory");
    else             asm volatile("s_waitcnt vmcnt(4)" ::: "memory");
    __builtin_amdgcn_s_barrier();
    const int kb = (kt & 1) * 16384;

    // ---- QK^T (32q x 64s)
    f32x4 sa[2][4] = {};
    __builtin_amdgcn_s_setprio(1);
    #pragma unroll
    for (int kk = 0; kk < 4; ++kk){
      bf16x8 bk[4];
      #pragma unroll
      for (int nn = 0; nn < 4; ++nn){
        int row = nn*16 + lr;
        bk[nn] = *(const bf16x8*)(KsB + kb + row*256 + (((kk*4 + lg) ^ (row & 7)) << 4));
      }
      #pragma unroll
      for (int mm = 0; mm < 2; ++mm)
        #pragma unroll
        for (int nn = 0; nn < 4; ++nn)
          sa[mm][nn] = __builtin_amdgcn_mfma_f32_16x16x32_bf16(aq[mm][kk], bk[nn], sa[mm][nn], 0,0,0);
    }
    __builtin_amdgcn_s_setprio(0);

    if (kt == lastkt){
      #pragma unroll
      for (int mm = 0; mm < 2; ++mm)
        #pragma unroll
        for (int nn = 0; nn < 4; ++nn)
          #pragma unroll
          for (int r = 0; r < 4; ++r){
            int srel = kt*64 + nn*16 + lr;
            int qrel = q0 + mm*16 + lg*4 + r;
            if (srel > qrel) sa[mm][nn][r] = -1e30f;
          }
    }

    // ---- online softmax over 64 cols
    float alph[2][4];
    #pragma unroll
    for (int mm = 0; mm < 2; ++mm)
      #pragma unroll
      for (int r = 0; r < 4; ++r){
        float v = fmaxf(fmaxf(sa[mm][0][r], sa[mm][1][r]), fmaxf(sa[mm][2][r], sa[mm][3][r]));
        v = fmaxf(v, __shfl_xor(v, 1));
        v = fmaxf(v, __shfl_xor(v, 2));
        v = fmaxf(v, __shfl_xor(v, 4));
        v = fmaxf(v, __shfl_xor(v, 8));
        float mn = fmaxf(mrun[mm][r], v);
        float al = __expf(mrun[mm][r] - mn);
        float rs = 0.f;
        #pragma unroll
        for (int nn = 0; nn < 4; ++nn){
          float p = __expf(sa[mm][nn][r] - mn);
          sa[mm][nn][r] = p;
          rs += p;
        }
        rs += __shfl_xor(rs, 1);
        rs += __shfl_xor(rs, 2);
        rs += __shfl_xor(rs, 4);
        rs += __shfl_xor(rs, 8);
        lrun[mm][r] = lrun[mm][r]*al + rs;
        mrun[mm][r] = mn;
        alph[mm][r] = al;
      }
    #pragma unroll
    for (int mm = 0; mm < 2; ++mm)
      #pragma unroll
      for (int df = 0; df < 8; ++df)
        #pragma unroll
        for (int r = 0; r < 4; ++r)
          oacc[mm][df][r] *= alph[mm][r];

    // ---- drain V(kt); keep K(kt+1) in flight
    if (kt < lastkt) asm volatile("s_waitcnt vmcnt(4)" ::: "memory");
    else             asm volatile("s_waitcnt vmcnt(0)" ::: "memory");
    __builtin_amdgcn_s_barrier();

    // ---- P -> per-wave LDS, reload as A-operand
    #pragma unroll
    for (int mm = 0; mm < 2; ++mm)
      #pragma unroll
      for (int nn = 0; nn < 4; ++nn)
        #pragma unroll
        for (int r = 0; r < 4; ++r)
          Psm[w][(mm*16 + lg*4 + r)*72 + nn*16 + lr] = f2bf(sa[mm][nn][r]);

    bf16x8 ap[2][2];
    #pragma unroll
    for (int mm = 0; mm < 2; ++mm)
      #pragma unroll
      for (int ks = 0; ks < 2; ++ks)
        ap[mm][ks] = *(const bf16x8*)(&Psm[w][(mm*16 + lr)*72 + ks*32 + lg*8]);

    // ---- PV
    __builtin_amdgcn_s_setprio(1);
    #pragma unroll
    for (int df = 0; df < 8; ++df){
      bf16x8 bv[2];
      #pragma unroll
      for (int ks = 0; ks < 2; ++ks){
        int d = df*16 + lr;
        bv[ks] = *(const bf16x8*)(VsB + d*128 + (((ks*4 + lg) ^ (d & 7)) << 4));
      }
      #pragma unroll
      for (int mm = 0; mm < 2; ++mm)
        #pragma unroll
        for (int ks = 0; ks < 2; ++ks)
          oacc[mm][df] = __builtin_amdgcn_mfma_f32_16x16x32_bf16(ap[mm][ks], bv[ks], oacc[mm][df], 0,0,0);
    }
    __builtin_amdgcn_s_setprio(0);

    asm volatile("" ::: "memory");
    __builtin_amdgcn_s_barrier();   // V consumed by all waves
    if (kt + 1 <= lastkt) STAGE_V(kt+1);
    if (kt + 2 <= lastkt) STAGE_K(kt+2);
  }
  #undef STAGE_K
  #undef STAGE_V

  #pragma unroll
  for (int mm = 0; mm < 2; ++mm)
    #pragma unroll
    for (int df = 0; df < 8; ++df)
      #pragma unroll
      for (int r = 0; r < 4; ++r){
        float val = oacc[mm][df][r] / lrun[mm][r];
        int t = q0 + mm*16 + lg*4 + r;
        int col = h*128 + df*16 + lr;
        ob[(size_t)t*O_COLS + col] = f2bf(val);
      }
}

extern "C" void kernel_launch(void* const* d_in, const int* in_sizes, int n_in,
                              void* d_out, int out_size, void* d_ws, size_t ws_size,
                              hipStream_t stream){
  const float* x  = (const float*)d_in[0];
  const int*   pos= (const int*)d_in[1];
  const float* Wq = (const float*)d_in[2];
  const float* Wk = (const float*)d_in[3];
  const float* Wv = (const float*)d_in[4];
  const float* Wo = (const float*)d_in[5];
  float* out = (float*)d_out;

  char* ws = (char*)d_ws;
  u16* xb   = (u16*)(ws);                 // 2048x8192 bf16   (32 MB)
  u16* wb   = (u16*)(ws + 33554432);      // 6144x8192 bf16   (96 MB)
  u16* wob  = (u16*)(ws + 134217728);     // 4096x4096 bf16   (32 MB)
  u16* qkv  = (u16*)(ws + 167772160);     // 2048x6144 bf16   (24 MB)
  u16* obuf = (u16*)(ws + 192937984);     // 2048x4096 bf16   (16 MB)
  u16* vtg  = (u16*)(ws + 209715200);     // 8x128x2048 bf16  (4 MB) V^T

  cvt_all<<<2048, 256, 0, stream>>>(x, Wq, Wk, Wv, Wo, xb, wb, wob);

  gemm_pipe<u16,3><<<256, 512, 0, stream>>>(xb, wb, qkv, IN_DIM, QKV_COLS, 32);
  transpose_v<<<dim3(32,8), 256, 0, stream>>>(qkv, vtg);
  rope_scale_kernel<<<T_SEQ, 256, 0, stream>>>(qkv, pos);
  attn2<<<dim3(64,8), 256, 0, stream>>>(qkv, vtg, obuf);
  gemm_pipe<float,2><<<256, 512, 0, stream>>>(obuf, wob, out, O_COLS, O_COLS, 32);
}